// Round 3
// baseline (302.359 us; speedup 1.0000x reference)
//
#include <hip/hip_runtime.h>
#include <hip/hip_bf16.h>

#define N_NODES 100000
#define N_EDGES 1600000
#define DIM_IN  256
#define DIM_H   128

#define NBKT 782          // ceil(N_NODES / 128) buckets of 128 nodes
#define CPAD 16           // ints per padded counter (one cacheline)
#define EPB  8192         // edges per build block
#define NBLK ((N_EDGES + EPB - 1) / EPB)   // 196

typedef __attribute__((ext_vector_type(8))) short short8;
typedef __attribute__((ext_vector_type(4))) float f32x4;

__device__ __forceinline__ int get_src(const int* e, int is64, int i) {
  return is64 ? e[2 * i] : e[i];
}
__device__ __forceinline__ int get_dst(const int* e, int is64, int i) {
  return is64 ? e[2 * (N_EDGES + i)] : e[N_EDGES + i];
}

// ------------------------------------ width detect + bcnt zero (merged)
__global__ __launch_bounds__(1024)
void k_init(const int* __restrict__ e, int* __restrict__ flag,
            int* __restrict__ bcnt) {
  if (blockIdx.x == 0) {
    __shared__ int s;
    if (threadIdx.x == 0) s = 0;
    __syncthreads();
    atomicOr(&s, e[2 * threadIdx.x + 1]);
    __syncthreads();
    if (threadIdx.x == 0) *flag = (s == 0) ? 1 : 0;
  } else {
    int i = (blockIdx.x - 1) * 1024 + threadIdx.x;
    if (i < NBKT * CPAD) bcnt[i] = 0;
  }
}

__global__ __launch_bounds__(256) void k_zero(int* __restrict__ p, int n) {
  int i = blockIdx.x * 256 + threadIdx.x;
  if (i < n) p[i] = 0;
}

// ---------------------------------------------------- bucketed CSR build
__global__ __launch_bounds__(1024)
void k_binc(const int* __restrict__ eidx, const int* __restrict__ flag,
            int* __restrict__ bcnt) {
  __shared__ int hist[NBKT];
  const int t = threadIdx.x;
  const int is64 = *flag;
  for (int i = t; i < NBKT; i += 1024) hist[i] = 0;
  __syncthreads();
#pragma unroll
  for (int j = 0; j < EPB / 1024; ++j) {
    int e = blockIdx.x * EPB + j * 1024 + t;
    if (e < N_EDGES) {
      unsigned s = (unsigned)get_src(eidx, is64, e);
      unsigned d = (unsigned)get_dst(eidx, is64, e);
      if (s < N_NODES && d < N_NODES) atomicAdd(&hist[d >> 7], 1);
    }
  }
  __syncthreads();
  for (int i = t; i < NBKT; i += 1024) {
    int h = hist[i];
    if (h) atomicAdd(&bcnt[i * CPAD], h);
  }
}

__global__ __launch_bounds__(1024)
void k_bscan(int* __restrict__ bcnt, int* __restrict__ bbase) {
  __shared__ int sm[1024];
  int t = threadIdx.x;
  int v = (t < NBKT) ? bcnt[t * CPAD] : 0;
  sm[t] = v;
  __syncthreads();
  for (int d = 1; d < 1024; d <<= 1) {
    int u = (t >= d) ? sm[t - d] : 0;
    __syncthreads();
    sm[t] += u;
    __syncthreads();
  }
  if (t < NBKT) {
    int excl = sm[t] - v;
    bbase[t] = excl;
    bcnt[t * CPAD] = excl;
    if (t == NBKT - 1) bbase[NBKT] = sm[t];
  }
}

// record = src | (d&127)<<17   (src < 2^17)
__global__ __launch_bounds__(1024)
void k_bin(const int* __restrict__ eidx, const int* __restrict__ flag,
           int* __restrict__ bcnt, unsigned* __restrict__ ebuf) {
  __shared__ int hist[NBKT];
  __shared__ int cur[NBKT];
  const int t = threadIdx.x;
  const int is64 = *flag;
  for (int i = t; i < NBKT; i += 1024) hist[i] = 0;
  unsigned rec[EPB / 1024];
  int bkt[EPB / 1024];
  __syncthreads();
#pragma unroll
  for (int j = 0; j < EPB / 1024; ++j) {
    int e = blockIdx.x * EPB + j * 1024 + t;
    bkt[j] = -1;
    rec[j] = 0;
    if (e < N_EDGES) {
      unsigned s = (unsigned)get_src(eidx, is64, e);
      unsigned d = (unsigned)get_dst(eidx, is64, e);
      if (s < N_NODES && d < N_NODES) {
        bkt[j] = (int)(d >> 7);
        rec[j] = s | ((d & 127u) << 17);
        atomicAdd(&hist[bkt[j]], 1);
      }
    }
  }
  __syncthreads();
  for (int i = t; i < NBKT; i += 1024) {
    int h = hist[i];
    cur[i] = h ? atomicAdd(&bcnt[i * CPAD], h) : 0;
  }
  __syncthreads();
#pragma unroll
  for (int j = 0; j < EPB / 1024; ++j) {
    if (bkt[j] >= 0) {
      int pos = atomicAdd(&cur[bkt[j]], 1);
      ebuf[pos] = rec[j];
    }
  }
}

__global__ __launch_bounds__(256)
void k_csr(const int* __restrict__ bbase, const unsigned* __restrict__ ebuf,
           int* __restrict__ off, float* __restrict__ dinv,
           int* __restrict__ csr) {
  __shared__ int hist[128];
  __shared__ int scn[128];
  __shared__ int cur[128];
  const int b = blockIdx.x, t = threadIdx.x;
  const int n0 = b << 7;
  const int start = bbase[b], end = bbase[b + 1];
  if (t < 128) hist[t] = 0;
  __syncthreads();
  for (int i = start + t; i < end; i += 256) {
    atomicAdd(&hist[ebuf[i] >> 17], 1);
  }
  __syncthreads();
  if (t < 128) scn[t] = hist[t];
  __syncthreads();
  for (int d = 1; d < 128; d <<= 1) {
    int u = (t < 128 && t >= d) ? scn[t - d] : 0;
    __syncthreads();
    if (t < 128) scn[t] += u;
    __syncthreads();
  }
  if (t < 128) {
    int node = n0 + t;
    if (node < N_NODES) {
      off[node] = start + scn[t];                    // ends
      dinv[node] = rsqrtf(1.0f + (float)hist[t]);
      cur[t] = start + scn[t] - hist[t];             // starts
    }
  }
  __syncthreads();
  for (int i = start + t; i < end; i += 256) {
    unsigned r = ebuf[i];
    int pos = atomicAdd(&cur[r >> 17], 1);
    csr[pos] = (int)(r & 0x1FFFFu);
  }
}

// ---------------------------------------------------------------- bf16 utils
__device__ __forceinline__ ushort f2bf(float f) {
  unsigned u = __float_as_uint(f);
  unsigned r = (u + 0x7fffu + ((u >> 16) & 1u)) >> 16;
  return (ushort)r;
}
__device__ __forceinline__ float bf2f(ushort h) {
  return __uint_as_float(((unsigned)h) << 16);
}

__device__ __forceinline__ void load8(const float* p, float* o) {
  float4 a = reinterpret_cast<const float4*>(p)[0];
  float4 b = reinterpret_cast<const float4*>(p)[1];
  o[0] = a.x; o[1] = a.y; o[2] = a.z; o[3] = a.w;
  o[4] = b.x; o[5] = b.y; o[6] = b.z; o[7] = b.w;
}

// Blocks 0..15: split Wi[256x128] into MFMA B-fragment planes (hi, lo).
// Block 16: fully collapsed tail weights
//   Wcc = W1 @ (W2 @ Wh)  [128 x 2]   (everything after h1 is linear)
//   c1  = b1 @ (W2 @ Wh)  [2]         stored at Wcc[256..257]
//   bc  = b2 @ Wh + bh    [2]         stored at Wcc[258..259]
__global__ __launch_bounds__(256)
void k_prep(const float* __restrict__ Wi, const float* __restrict__ W1,
            const float* __restrict__ W2, const float* __restrict__ Wh,
            const float* __restrict__ b1, const float* __restrict__ b2,
            const float* __restrict__ bh, ushort* __restrict__ outHi,
            float* __restrict__ Wcc) {
  __shared__ float Wc2s[DIM_H][2];
  constexpr int CH = DIM_IN / 32;   // 8
  if (blockIdx.x == 16) {
    const int t = threadIdx.x;
    const int i = t >> 1, j = t & 1;
    float s = 0.f;
#pragma unroll 4
    for (int m = 0; m < DIM_H; ++m) s += W2[(size_t)i * DIM_H + m] * Wh[m * 2 + j];
    Wc2s[i][j] = s;
    __syncthreads();
    float c = 0.f;
#pragma unroll 4
    for (int k = 0; k < DIM_H; ++k) c += W1[(size_t)i * DIM_H + k] * Wc2s[k][j];
    Wcc[i * 2 + j] = c;
    if (t < 2) {
      float a = 0.f, b = 0.f;
      for (int k = 0; k < DIM_H; ++k) {
        a += b1[k] * Wc2s[k][t];
        b += b2[k] * Wh[k * 2 + t];
      }
      Wcc[256 + t] = a;           // c1
      Wcc[258 + t] = b + bh[t];   // bc
    }
    return;
  }
  int idx = blockIdx.x * 256 + threadIdx.x;   // < CH*512 = 4096
  int n  = idx & 15;
  int qq = (idx >> 4) & 3;
  int nt = (idx >> 6) & 7;
  int c  = idx >> 9;
  int col = nt * 16 + n;
  short8 h8, l8;
#pragma unroll
  for (int j = 0; j < 8; ++j) {
    float v = Wi[(size_t)(c * 32 + qq * 8 + j) * DIM_H + col];
    ushort hb = f2bf(v);
    ushort lb = f2bf(v - bf2f(hb));
    h8[j] = (short)hb;
    l8[j] = (short)lb;
  }
  ((short8*)outHi)[idx] = h8;
  ((short8*)outHi)[CH * 512 + idx] = l8;
}

// ------------- Barrier-free MFMA GEMM + fused z = relu(.)@Wcc epilogue.
// Each wave independently owns 16 rows x all 128 cols: A-fragments loaded
// straight from global in MFMA lane layout (lane = row m_l, quad = k-sub),
// hi/lo split in-register, zero LDS, zero __syncthreads.
// Emits tbl[row] = (dinv*z0, dinv*z1, dinv, 0); h1 never materialized.
template <int K>
__global__ __launch_bounds__(256)
void k_gemm_xz(const float* __restrict__ A, const ushort* __restrict__ Bfrag,
               const float* __restrict__ bias, const float* __restrict__ Wcc,
               const float* __restrict__ dinv, float4* __restrict__ tbl) {
  constexpr int CH = K / 32;   // 8
  const int tid = threadIdx.x;
  const int wave = tid >> 6, lane = tid & 63;
  const int m_l = lane & 15, quad = lane >> 4;
  const int mrow = blockIdx.x * 64 + wave * 16;   // wave's row base

  f32x4 acc[8];
#pragma unroll
  for (int nt = 0; nt < 8; ++nt) acc[nt] = (f32x4){0.f, 0.f, 0.f, 0.f};

  const short8* Bhi8 = (const short8*)Bfrag;
  const short8* Blo8 = Bhi8 + CH * 512;

  // clamp OOB rows to a valid address; their C rows are write-guarded out
  const int rowc = (mrow + m_l < N_NODES) ? (mrow + m_l) : (N_NODES - 1);
  const float* Ap = &A[(size_t)rowc * K + quad * 8];

#pragma unroll 2
  for (int c = 0; c < CH; ++c) {
    float v[8];
    load8(Ap + c * 32, v);
    short8 ahi, alo;
#pragma unroll
    for (int j = 0; j < 8; ++j) {
      ushort hb = f2bf(v[j]);
      ushort lb = f2bf(v[j] - bf2f(hb));
      ahi[j] = (short)hb;
      alo[j] = (short)lb;
    }
#pragma unroll
    for (int nt = 0; nt < 8; ++nt) {
      const int bent = ((c * 8 + nt) * 4 + quad) * 16 + m_l;
      short8 bhi = Bhi8[bent];
      short8 blo = Blo8[bent];
      acc[nt] = __builtin_amdgcn_mfma_f32_16x16x32_bf16(ahi, bhi, acc[nt], 0, 0, 0);
      acc[nt] = __builtin_amdgcn_mfma_f32_16x16x32_bf16(ahi, blo, acc[nt], 0, 0, 0);
      acc[nt] = __builtin_amdgcn_mfma_f32_16x16x32_bf16(alo, bhi, acc[nt], 0, 0, 0);
    }
  }

  // ---- fused epilogue: p = relu(acc + bias) @ Wcc, reduced over 128 cols
  float p0[4], p1[4];
#pragma unroll
  for (int r = 0; r < 4; ++r) { p0[r] = 0.f; p1[r] = 0.f; }
#pragma unroll
  for (int nt = 0; nt < 8; ++nt) {
    const int colg = nt * 16 + m_l;
    const float bv = bias[colg];
    const float w0 = Wcc[colg * 2 + 0];
    const float w1 = Wcc[colg * 2 + 1];
#pragma unroll
    for (int r = 0; r < 4; ++r) {
      float hv = fmaxf(acc[nt][r] + bv, 0.f);   // relu(h1)
      p0[r] += hv * w0;
      p1[r] += hv * w1;
    }
  }
  // reduce across the 16 m_l lanes (cols); lanes l, l^o share quad for o<16
#pragma unroll
  for (int o = 1; o < 16; o <<= 1) {
#pragma unroll
    for (int r = 0; r < 4; ++r) {
      p0[r] += __shfl_xor(p0[r], o);
      p1[r] += __shfl_xor(p1[r], o);
    }
  }
  if (m_l == 0) {
#pragma unroll
    for (int r = 0; r < 4; ++r) {
      const int rowg = mrow + quad * 4 + r;
      if (rowg < N_NODES) {
        float dn = dinv[rowg];
        tbl[rowg] = make_float4(dn * p0[r], dn * p1[r], dn, 0.f);
      }
    }
  }
}

// ---------------- pass 1: yt[d] = dinv²·(zs[d] + Σ zs[s]),  g[d] = dinv·(Σ dinv + dinv)
// tbl[s] = (zs0, zs1, dinv[s], 0), 16 B/edge gather on a 1.6 MB (L2-resident) table.
__global__ __launch_bounds__(256)
void k_aggr1(const int* __restrict__ off, const int* __restrict__ csr,
             const float4* __restrict__ tbl, float2* __restrict__ tb2,
             float* __restrict__ g) {
  int node = blockIdx.x * 256 + threadIdx.x;
  if (node >= N_NODES) return;
  int start = (node == 0) ? 0 : off[node - 1];
  int end = off[node];
  float4 self = tbl[node];
  float s0 = self.x, s1 = self.y, sd = self.z;
  int e = start;
  for (; e + 3 < end; e += 4) {
    int i0 = csr[e], i1 = csr[e + 1], i2 = csr[e + 2], i3 = csr[e + 3];
    float4 v0 = tbl[i0];
    float4 v1 = tbl[i1];
    float4 v2 = tbl[i2];
    float4 v3 = tbl[i3];
    s0 += (v0.x + v1.x) + (v2.x + v3.x);
    s1 += (v0.y + v1.y) + (v2.y + v3.y);
    sd += (v0.z + v1.z) + (v2.z + v3.z);
  }
  for (; e < end; ++e) {
    float4 v = tbl[csr[e]];
    s0 += v.x; s1 += v.y; sd += v.z;
  }
  float dn = self.z;
  tb2[node] = make_float2(dn * dn * s0, dn * dn * s1);
  g[node] = dn * sd;
}

// ---------------- pass 2: out[d] = dinv·(yt[d] + Σ yt[s]) + g[d]·c1 + bc
// 8 B/edge gather on an 800 KB table. tail = {c1[0],c1[1],bc[0],bc[1]}.
__global__ __launch_bounds__(256)
void k_aggr2(const int* __restrict__ off, const int* __restrict__ csr,
             const float2* __restrict__ tb2, const float* __restrict__ dinv,
             const float* __restrict__ g, const float* __restrict__ tail,
             float* __restrict__ out) {
  int node = blockIdx.x * 256 + threadIdx.x;
  if (node >= N_NODES) return;
  int start = (node == 0) ? 0 : off[node - 1];
  int end = off[node];
  float2 self = tb2[node];
  float s0 = self.x, s1 = self.y;
  int e = start;
  for (; e + 3 < end; e += 4) {
    int i0 = csr[e], i1 = csr[e + 1], i2 = csr[e + 2], i3 = csr[e + 3];
    float2 v0 = tb2[i0];
    float2 v1 = tb2[i1];
    float2 v2 = tb2[i2];
    float2 v3 = tb2[i3];
    s0 += (v0.x + v1.x) + (v2.x + v3.x);
    s1 += (v0.y + v1.y) + (v2.y + v3.y);
  }
  for (; e < end; ++e) {
    float2 v = tb2[csr[e]];
    s0 += v.x; s1 += v.y;
  }
  float dn = dinv[node], gv = g[node];
  float o0 = dn * s0 + gv * tail[0] + tail[2];
  float o1 = dn * s1 + gv * tail[1] + tail[3];
  reinterpret_cast<float2*>(out)[node] = make_float2(o0, o1);
}

// --------------------------------------------- fp32 fallback (small ws) ----
__global__ __launch_bounds__(256) void k_count(const int* __restrict__ eidx,
                                               const int* __restrict__ flag,
                                               int* __restrict__ off) {
  int e = blockIdx.x * 256 + threadIdx.x;
  int is64 = *flag;
  if (e < N_EDGES) {
    unsigned d = (unsigned)get_dst(eidx, is64, e);
    if (d < N_NODES) atomicAdd(&off[d], 1);
  }
}

__global__ __launch_bounds__(256) void k_dinv_old(const int* __restrict__ off,
                                                  float* __restrict__ dinv) {
  int i = blockIdx.x * 256 + threadIdx.x;
  if (i < N_NODES) dinv[i] = rsqrtf(1.0f + (float)off[i]);
}

template <int K>
__global__ __launch_bounds__(256)
void k_gemm(const float* __restrict__ A, const float* __restrict__ B,
            const float* __restrict__ bias, const float* __restrict__ scale,
            float* __restrict__ C, const int do_relu) {
  __shared__ float As[64][33];
  const int tid = threadIdx.x;
  const int tx = tid & 15;
  const int ty = tid >> 4;
  const int m0 = blockIdx.x * 64;

  float acc[4][8];
#pragma unroll
  for (int i = 0; i < 4; ++i)
#pragma unroll
    for (int j = 0; j < 8; ++j) acc[i][j] = 0.f;

  const int rs = tid >> 2;
  const int ks = (tid & 3) * 8;

  for (int k0 = 0; k0 < K; k0 += 32) {
    float av8[8];
    const int gm = m0 + rs;
    if (gm < N_NODES) {
      load8(&A[(size_t)gm * K + k0 + ks], av8);
    } else {
#pragma unroll
      for (int j = 0; j < 8; ++j) av8[j] = 0.f;
    }
    __syncthreads();
#pragma unroll
    for (int j = 0; j < 8; ++j) As[rs][ks + j] = av8[j];
    __syncthreads();

    const float* Bp = B + (size_t)k0 * DIM_H + tx * 8;
#pragma unroll 4
    for (int k = 0; k < 32; ++k) {
      float bv[8];
      load8(Bp + (size_t)k * DIM_H, bv);
      float av[4];
#pragma unroll
      for (int rr = 0; rr < 4; ++rr) av[rr] = As[ty * 4 + rr][k];
#pragma unroll
      for (int rr = 0; rr < 4; ++rr)
#pragma unroll
        for (int cc = 0; cc < 8; ++cc)
          acc[rr][cc] = fmaf(av[rr], bv[cc], acc[rr][cc]);
    }
  }

  float bs[8];
  if (bias) {
    load8(bias + tx * 8, bs);
  } else {
#pragma unroll
    for (int j = 0; j < 8; ++j) bs[j] = 0.f;
  }
#pragma unroll
  for (int rr = 0; rr < 4; ++rr) {
    const int gm = m0 + ty * 4 + rr;
    if (gm < N_NODES) {
      float sc = scale ? scale[gm] : 1.0f;
      float v[8];
#pragma unroll
      for (int cc = 0; cc < 8; ++cc) {
        float t = acc[rr][cc] + bs[cc];
        if (do_relu) t = fmaxf(t, 0.f);
        v[cc] = t * sc;
      }
      float* Cp = &C[(size_t)gm * DIM_H + tx * 8];
      reinterpret_cast<float4*>(Cp)[0] = make_float4(v[0], v[1], v[2], v[3]);
      reinterpret_cast<float4*>(Cp)[1] = make_float4(v[4], v[5], v[6], v[7]);
    }
  }
}

__global__ __launch_bounds__(256)
void k_aggr_init(const float* __restrict__ t, const float* __restrict__ dinv,
                 const float* __restrict__ bias, float* __restrict__ h) {
  int idx = blockIdx.x * 256 + threadIdx.x;
  if (idx < N_NODES * DIM_H) {
    int i = idx >> 7;
    int c = idx & 127;
    float d = dinv[i];
    h[idx] = bias[c] + t[idx] * d * d;
  }
}

__global__ __launch_bounds__(256)
void k_aggr_edges(const int* __restrict__ eidx, const int* __restrict__ flag,
                  const float* __restrict__ t, const float* __restrict__ dinv,
                  float* __restrict__ h) {
  int e = blockIdx.x * 2 + (threadIdx.x >> 7);
  int c = threadIdx.x & 127;
  int is64 = *flag;
  if (e < N_EDGES) {
    unsigned s = (unsigned)get_src(eidx, is64, e);
    unsigned d = (unsigned)get_dst(eidx, is64, e);
    if (s < N_NODES && d < N_NODES) {
      float nrm = dinv[s] * dinv[d];
      unsafeAtomicAdd(&h[(size_t)d * DIM_H + c], t[(size_t)s * DIM_H + c] * nrm);
    }
  }
}

__global__ __launch_bounds__(256)
void k_head_f32(const float* __restrict__ h, const float* __restrict__ Wh,
                const float* __restrict__ bh, float* __restrict__ out) {
  int node = blockIdx.x * 4 + (threadIdx.x >> 6);
  int lane = threadIdx.x & 63;
  if (node >= N_NODES) return;
  float h0 = h[(size_t)node * DIM_H + lane];
  float h1 = h[(size_t)node * DIM_H + 64 + lane];
  float s0 = h0 * Wh[lane * 2 + 0] + h1 * Wh[(lane + 64) * 2 + 0];
  float s1 = h0 * Wh[lane * 2 + 1] + h1 * Wh[(lane + 64) * 2 + 1];
#pragma unroll
  for (int off = 32; off > 0; off >>= 1) {
    s0 += __shfl_down(s0, off);
    s1 += __shfl_down(s1, off);
  }
  if (lane == 0) {
    reinterpret_cast<float2*>(out)[node] = make_float2(s0 + bh[0], s1 + bh[1]);
  }
}

// ---------------------------------------------------------------- launch
extern "C" void kernel_launch(void* const* d_in, const int* in_sizes, int n_in,
                              void* d_out, int out_size, void* d_ws, size_t ws_size,
                              hipStream_t stream) {
  (void)in_sizes; (void)n_in; (void)out_size;
  const int* eidx = (const int*)d_in[0];
  const float* x  = (const float*)d_in[1];
  const float* Wi = (const float*)d_in[2];
  const float* bi = (const float*)d_in[3];
  const float* W1 = (const float*)d_in[4];
  const float* b1 = (const float*)d_in[5];
  const float* W2 = (const float*)d_in[6];
  const float* b2 = (const float*)d_in[7];
  const float* Wh = (const float*)d_in[8];
  const float* bh = (const float*)d_in[9];
  float* out = (float*)d_out;

  const int gE  = (N_EDGES + 255) / 256;
  const int gM  = (N_NODES + 63) / 64;
  const int gW  = (N_NODES + 3) / 4;
  const int gN256 = (N_NODES + 255) / 256;

  char* ws = (char*)d_ws;
  int* flag = (int*)ws;

  const size_t need1 = 17410048;

  if (ws_size >= need1) {
    int*      bcnt  = (int*)(ws + 4096);
    int*      bbase = (int*)(ws + 57344);
    float*    Wcc   = (float*)(ws + 61440);     // 128x2 + c1[2] + bc[2]
    ushort*   bfWi  = (ushort*)(ws + 65536);    // 131072 B
    int*      off   = (int*)(ws + 262144);      // 400000 B
    float*    dinv  = (float*)(ws + 720896);    // 400000 B
    float*    g     = (float*)(ws + 1179648);   // 400000 B
    float4*   tbl   = (float4*)(ws + 1638400);  // 1600000 B
    float2*   tb2   = (float2*)(ws + 3407872);  // 800000 B
    int*      csr   = (int*)(ws + 4456448);     // 6400000 B
    unsigned* ebuf  = (unsigned*)(ws + 11010048); // 6400000 B

    // detect + bcnt zero (merged); bucketed CSR build
    k_init<<<1 + (NBKT * CPAD + 1023) / 1024, 1024, 0, stream>>>(eidx, flag, bcnt);
    k_binc<<<NBLK, 1024, 0, stream>>>(eidx, flag, bcnt);
    k_bscan<<<1, 1024, 0, stream>>>(bcnt, bbase);
    k_bin<<<NBLK, 1024, 0, stream>>>(eidx, flag, bcnt, ebuf);
    k_csr<<<NBKT, 256, 0, stream>>>(bbase, ebuf, off, dinv, csr);

    // weight prep: Wi fragments + collapsed tail Wcc = W1@W2@Wh (merged)
    k_prep<<<17, 256, 0, stream>>>(Wi, W1, W2, Wh, b1, b2, bh, bfWi, Wcc);

    // z = relu(x@Wi+bi) @ Wcc fused into GEMM epilogue -> tbl (N x float4)
    k_gemm_xz<DIM_IN><<<gM, 256, 0, stream>>>(x, bfWi, bi, Wcc, dinv, tbl);
    // two cheap 8-16 B/edge aggregation passes (L2-resident tables)
    k_aggr1<<<gN256, 256, 0, stream>>>(off, csr, tbl, tb2, g);
    k_aggr2<<<gN256, 256, 0, stream>>>(off, csr, tb2, dinv, g, Wcc + 256, out);
  } else {
    // fallback: fp32 atomic-scatter path (~103 MB)
    const int gN  = (N_NODES + 255) / 256;
    int*   off  = (int*)(ws + 4096);
    float* dinv = (float*)(ws + 404480);
    float* fbA  = (float*)(ws + 804864);
    float* fbB  = (float*)(ws + 804864 + (size_t)N_NODES * DIM_H * 4);
    const int gNH = (N_NODES * DIM_H + 255) / 256;
    const int gE2 = (N_EDGES + 1) / 2;
    k_init<<<1, 1024, 0, stream>>>(eidx, flag, (int*)(ws + 4096));
    k_zero<<<gN, 256, 0, stream>>>(off, N_NODES);
    k_count<<<gE, 256, 0, stream>>>(eidx, flag, off);
    k_dinv_old<<<gN, 256, 0, stream>>>(off, dinv);

    k_gemm<DIM_IN><<<gM, 256, 0, stream>>>(x, Wi, bi, nullptr, fbA, 1);
    k_gemm<DIM_H><<<gM, 256, 0, stream>>>(fbA, W1, nullptr, nullptr, fbB, 0);
    k_aggr_init<<<gNH, 256, 0, stream>>>(fbB, dinv, b1, fbA);
    k_aggr_edges<<<gE2, 256, 0, stream>>>(eidx, flag, fbB, dinv, fbA);
    k_gemm<DIM_H><<<gM, 256, 0, stream>>>(fbA, W2, nullptr, nullptr, fbB, 0);
    k_aggr_init<<<gNH, 256, 0, stream>>>(fbB, dinv, b2, fbA);
    k_aggr_edges<<<gE2, 256, 0, stream>>>(eidx, flag, fbB, dinv, fbA);
    k_head_f32<<<gW, 256, 0, stream>>>(fbA, Wh, bh, out);
  }
}

// Round 4
// 294.538 us; speedup vs baseline: 1.0266x; 1.0266x over previous
//
#include <hip/hip_runtime.h>
#include <hip/hip_bf16.h>

#define N_NODES 100000
#define N_EDGES 1600000
#define DIM_IN  256
#define DIM_H   128

#define NBKT 782          // ceil(N_NODES / 128) buckets of 128 nodes
#define CPAD 16           // ints per padded counter (one cacheline)
#define EPB  8192         // edges per build block
#define NBLK ((N_EDGES + EPB - 1) / EPB)   // 196

typedef __attribute__((ext_vector_type(8))) short short8;
typedef __attribute__((ext_vector_type(4))) float f32x4;

__device__ __forceinline__ int get_src(const int* e, int is64, int i) {
  return is64 ? e[2 * i] : e[i];
}
__device__ __forceinline__ int get_dst(const int* e, int is64, int i) {
  return is64 ? e[2 * (N_EDGES + i)] : e[N_EDGES + i];
}

// ------------------------------------ width detect + bcnt zero (merged)
__global__ __launch_bounds__(1024)
void k_init(const int* __restrict__ e, int* __restrict__ flag,
            int* __restrict__ bcnt) {
  if (blockIdx.x == 0) {
    __shared__ int s;
    if (threadIdx.x == 0) s = 0;
    __syncthreads();
    atomicOr(&s, e[2 * threadIdx.x + 1]);
    __syncthreads();
    if (threadIdx.x == 0) *flag = (s == 0) ? 1 : 0;
  } else {
    int i = (blockIdx.x - 1) * 1024 + threadIdx.x;
    if (i < NBKT * CPAD) bcnt[i] = 0;
  }
}

__global__ __launch_bounds__(256) void k_zero(int* __restrict__ p, int n) {
  int i = blockIdx.x * 256 + threadIdx.x;
  if (i < n) p[i] = 0;
}

// ---------------------------------------------------- bucketed CSR build
__global__ __launch_bounds__(1024)
void k_binc(const int* __restrict__ eidx, const int* __restrict__ flag,
            int* __restrict__ bcnt) {
  __shared__ int hist[NBKT];
  const int t = threadIdx.x;
  const int is64 = *flag;
  for (int i = t; i < NBKT; i += 1024) hist[i] = 0;
  __syncthreads();
#pragma unroll
  for (int j = 0; j < EPB / 1024; ++j) {
    int e = blockIdx.x * EPB + j * 1024 + t;
    if (e < N_EDGES) {
      unsigned s = (unsigned)get_src(eidx, is64, e);
      unsigned d = (unsigned)get_dst(eidx, is64, e);
      if (s < N_NODES && d < N_NODES) atomicAdd(&hist[d >> 7], 1);
    }
  }
  __syncthreads();
  for (int i = t; i < NBKT; i += 1024) {
    int h = hist[i];
    if (h) atomicAdd(&bcnt[i * CPAD], h);
  }
}

__global__ __launch_bounds__(1024)
void k_bscan(int* __restrict__ bcnt, int* __restrict__ bbase) {
  __shared__ int sm[1024];
  int t = threadIdx.x;
  int v = (t < NBKT) ? bcnt[t * CPAD] : 0;
  sm[t] = v;
  __syncthreads();
  for (int d = 1; d < 1024; d <<= 1) {
    int u = (t >= d) ? sm[t - d] : 0;
    __syncthreads();
    sm[t] += u;
    __syncthreads();
  }
  if (t < NBKT) {
    int excl = sm[t] - v;
    bbase[t] = excl;
    bcnt[t * CPAD] = excl;
    if (t == NBKT - 1) bbase[NBKT] = sm[t];
  }
}

// record = src | (d&127)<<17   (src < 2^17)
__global__ __launch_bounds__(1024)
void k_bin(const int* __restrict__ eidx, const int* __restrict__ flag,
           int* __restrict__ bcnt, unsigned* __restrict__ ebuf) {
  __shared__ int hist[NBKT];
  __shared__ int cur[NBKT];
  const int t = threadIdx.x;
  const int is64 = *flag;
  for (int i = t; i < NBKT; i += 1024) hist[i] = 0;
  unsigned rec[EPB / 1024];
  int bkt[EPB / 1024];
  __syncthreads();
#pragma unroll
  for (int j = 0; j < EPB / 1024; ++j) {
    int e = blockIdx.x * EPB + j * 1024 + t;
    bkt[j] = -1;
    rec[j] = 0;
    if (e < N_EDGES) {
      unsigned s = (unsigned)get_src(eidx, is64, e);
      unsigned d = (unsigned)get_dst(eidx, is64, e);
      if (s < N_NODES && d < N_NODES) {
        bkt[j] = (int)(d >> 7);
        rec[j] = s | ((d & 127u) << 17);
        atomicAdd(&hist[bkt[j]], 1);
      }
    }
  }
  __syncthreads();
  for (int i = t; i < NBKT; i += 1024) {
    int h = hist[i];
    cur[i] = h ? atomicAdd(&bcnt[i * CPAD], h) : 0;
  }
  __syncthreads();
#pragma unroll
  for (int j = 0; j < EPB / 1024; ++j) {
    if (bkt[j] >= 0) {
      int pos = atomicAdd(&cur[bkt[j]], 1);
      ebuf[pos] = rec[j];
    }
  }
}

__global__ __launch_bounds__(256)
void k_csr(const int* __restrict__ bbase, const unsigned* __restrict__ ebuf,
           int* __restrict__ off, float* __restrict__ dinv,
           int* __restrict__ csr) {
  __shared__ int hist[128];
  __shared__ int scn[128];
  __shared__ int cur[128];
  const int b = blockIdx.x, t = threadIdx.x;
  const int n0 = b << 7;
  const int start = bbase[b], end = bbase[b + 1];
  if (t < 128) hist[t] = 0;
  __syncthreads();
  for (int i = start + t; i < end; i += 256) {
    atomicAdd(&hist[ebuf[i] >> 17], 1);
  }
  __syncthreads();
  if (t < 128) scn[t] = hist[t];
  __syncthreads();
  for (int d = 1; d < 128; d <<= 1) {
    int u = (t < 128 && t >= d) ? scn[t - d] : 0;
    __syncthreads();
    if (t < 128) scn[t] += u;
    __syncthreads();
  }
  if (t < 128) {
    int node = n0 + t;
    if (node < N_NODES) {
      off[node] = start + scn[t];                    // ends
      dinv[node] = rsqrtf(1.0f + (float)hist[t]);
      cur[t] = start + scn[t] - hist[t];             // starts
    }
  }
  __syncthreads();
  for (int i = start + t; i < end; i += 256) {
    unsigned r = ebuf[i];
    int pos = atomicAdd(&cur[r >> 17], 1);
    csr[pos] = (int)(r & 0x1FFFFu);
  }
}

// ---------------------------------------------------------------- bf16 utils
__device__ __forceinline__ ushort f2bf(float f) {
  unsigned u = __float_as_uint(f);
  unsigned r = (u + 0x7fffu + ((u >> 16) & 1u)) >> 16;
  return (ushort)r;
}
__device__ __forceinline__ float bf2f(ushort h) {
  return __uint_as_float(((unsigned)h) << 16);
}

__device__ __forceinline__ void load8(const float* p, float* o) {
  float4 a = reinterpret_cast<const float4*>(p)[0];
  float4 b = reinterpret_cast<const float4*>(p)[1];
  o[0] = a.x; o[1] = a.y; o[2] = a.z; o[3] = a.w;
  o[4] = b.x; o[5] = b.y; o[6] = b.z; o[7] = b.w;
}

__device__ __forceinline__ void cvt_split(const float* v, short8& h, short8& l) {
#pragma unroll
  for (int j = 0; j < 8; ++j) {
    ushort hb = f2bf(v[j]);
    ushort lb = f2bf(v[j] - bf2f(hb));
    h[j] = (short)hb;
    l[j] = (short)lb;
  }
}

// Blocks 0..15: split Wi[256x128] into MFMA B-fragment planes (hi, lo).
// Block 16: fully collapsed tail weights
//   Wcc = W1 @ (W2 @ Wh)  [128 x 2]   (everything after h1 is linear)
//   c1  = b1 @ (W2 @ Wh)  [2]         stored at Wcc[256..257]
//   bc  = b2 @ Wh + bh    [2]         stored at Wcc[258..259]
__global__ __launch_bounds__(256)
void k_prep(const float* __restrict__ Wi, const float* __restrict__ W1,
            const float* __restrict__ W2, const float* __restrict__ Wh,
            const float* __restrict__ b1, const float* __restrict__ b2,
            const float* __restrict__ bh, ushort* __restrict__ outHi,
            float* __restrict__ Wcc) {
  __shared__ float Wc2s[DIM_H][2];
  constexpr int CH = DIM_IN / 32;   // 8
  if (blockIdx.x == 16) {
    const int t = threadIdx.x;
    const int i = t >> 1, j = t & 1;
    float s = 0.f;
#pragma unroll 4
    for (int m = 0; m < DIM_H; ++m) s += W2[(size_t)i * DIM_H + m] * Wh[m * 2 + j];
    Wc2s[i][j] = s;
    __syncthreads();
    float c = 0.f;
#pragma unroll 4
    for (int k = 0; k < DIM_H; ++k) c += W1[(size_t)i * DIM_H + k] * Wc2s[k][j];
    Wcc[i * 2 + j] = c;
    if (t < 2) {
      float a = 0.f, b = 0.f;
      for (int k = 0; k < DIM_H; ++k) {
        a += b1[k] * Wc2s[k][t];
        b += b2[k] * Wh[k * 2 + t];
      }
      Wcc[256 + t] = a;           // c1
      Wcc[258 + t] = b + bh[t];   // bc
    }
    return;
  }
  int idx = blockIdx.x * 256 + threadIdx.x;   // < CH*512 = 4096
  int n  = idx & 15;
  int qq = (idx >> 4) & 3;
  int nt = (idx >> 6) & 7;
  int c  = idx >> 9;
  int col = nt * 16 + n;
  short8 h8, l8;
#pragma unroll
  for (int j = 0; j < 8; ++j) {
    float v = Wi[(size_t)(c * 32 + qq * 8 + j) * DIM_H + col];
    ushort hb = f2bf(v);
    ushort lb = f2bf(v - bf2f(hb));
    h8[j] = (short)hb;
    l8[j] = (short)lb;
  }
  ((short8*)outHi)[idx] = h8;
  ((short8*)outHi)[CH * 512 + idx] = l8;
}

// ------------- Cooperative MFMA GEMM, 128-row tile, double-buffered LDS,
// one barrier per K-step, global->reg prefetch; fused z = relu(.)@Wcc.
// 4 waves: each wave = 8 m-tiles x 2 col-tiles (48 MFMA / K-step).
// A staged via LDS (hi/lo planes), B-fragments read per-wave from L2.
// Emits tbl[row] = (dinv*z0, dinv*z1, dinv, 0); h1 never materialized.
template <int K>
__global__ __launch_bounds__(256, 3)
void k_gemm_xz(const float* __restrict__ A, const ushort* __restrict__ Bfrag,
               const float* __restrict__ bias, const float* __restrict__ Wcc,
               const float* __restrict__ dinv, float4* __restrict__ tbl) {
  constexpr int CH = K / 32;   // 8
  // staging: [buf][entry], entry = (row>>4)*64 + q*16 + (row&15), 512 entries
  __shared__ __align__(16) ushort AhiS[2][512 * 8];
  __shared__ __align__(16) ushort AloS[2][512 * 8];
  const int tid = threadIdx.x;
  const int m0 = blockIdx.x * 128;
  const int wave = tid >> 6, lane = tid & 63;
  const int m_l = lane & 15, quad = lane >> 4;
  const int rs = tid >> 2, q = tid & 3;

  f32x4 acc[2][8];
#pragma unroll
  for (int i = 0; i < 2; ++i)
#pragma unroll
    for (int j = 0; j < 8; ++j) acc[i][j] = (f32x4){0.f, 0.f, 0.f, 0.f};

  const short8* Bhi8 = (const short8*)Bfrag;
  const short8* Blo8 = Bhi8 + CH * 512;
  short8* Ah = (short8*)AhiS;
  short8* Al = (short8*)AloS;

  // staging rows: r0 = rs, r1 = rs + 64 (clamp OOB; writes guarded later)
  const int gr0 = m0 + rs, gr1 = m0 + rs + 64;
  const float* Ap0 = &A[(size_t)((gr0 < N_NODES) ? gr0 : (N_NODES - 1)) * K + q * 8];
  const float* Ap1 = &A[(size_t)((gr1 < N_NODES) ? gr1 : (N_NODES - 1)) * K + q * 8];
  const int ent0 = (rs >> 4) * 64 + q * 16 + (rs & 15);
  const int ent1 = ent0 + 256;

  // prologue: load + convert + store c=0 into buf 0
  {
    float v0[8], v1[8];
    load8(Ap0, v0);
    load8(Ap1, v1);
    short8 h, l;
    cvt_split(v0, h, l);
    Ah[ent0] = h; Al[ent0] = l;
    cvt_split(v1, h, l);
    Ah[ent1] = h; Al[ent1] = l;
  }
  __syncthreads();

#pragma unroll
  for (int c = 0; c < CH; ++c) {
    const int cur = c & 1, nxt = cur ^ 1;
    // prefetch next K-chunk into registers (global, overlaps MFMAs)
    float v0n[8], v1n[8];
    if (c + 1 < CH) {
      load8(Ap0 + (c + 1) * 32, v0n);
      load8(Ap1 + (c + 1) * 32, v1n);
    }
    // this wave's B fragments (2 col-tiles)
    const int bent0 = ((c * 8 + wave * 2 + 0) * 4 + quad) * 16 + m_l;
    const int bent1 = ((c * 8 + wave * 2 + 1) * 4 + quad) * 16 + m_l;
    short8 bhi0 = Bhi8[bent0], blo0 = Blo8[bent0];
    short8 bhi1 = Bhi8[bent1], blo1 = Blo8[bent1];
    const short8* AhC = Ah + cur * 512;
    const short8* AlC = Al + cur * 512;
#pragma unroll
    for (int mt = 0; mt < 8; ++mt) {
      short8 ahi = AhC[mt * 64 + quad * 16 + m_l];
      short8 alo = AlC[mt * 64 + quad * 16 + m_l];
      acc[0][mt] = __builtin_amdgcn_mfma_f32_16x16x32_bf16(ahi, bhi0, acc[0][mt], 0, 0, 0);
      acc[0][mt] = __builtin_amdgcn_mfma_f32_16x16x32_bf16(ahi, blo0, acc[0][mt], 0, 0, 0);
      acc[0][mt] = __builtin_amdgcn_mfma_f32_16x16x32_bf16(alo, bhi0, acc[0][mt], 0, 0, 0);
      acc[1][mt] = __builtin_amdgcn_mfma_f32_16x16x32_bf16(ahi, bhi1, acc[1][mt], 0, 0, 0);
      acc[1][mt] = __builtin_amdgcn_mfma_f32_16x16x32_bf16(ahi, blo1, acc[1][mt], 0, 0, 0);
      acc[1][mt] = __builtin_amdgcn_mfma_f32_16x16x32_bf16(alo, bhi1, acc[1][mt], 0, 0, 0);
    }
    // convert + store next chunk into the other buffer, then single barrier
    if (c + 1 < CH) {
      short8 h, l;
      cvt_split(v0n, h, l);
      Ah[nxt * 512 + ent0] = h; Al[nxt * 512 + ent0] = l;
      cvt_split(v1n, h, l);
      Ah[nxt * 512 + ent1] = h; Al[nxt * 512 + ent1] = l;
    }
    __syncthreads();
  }

  // ---- fused epilogue: p = relu(acc + bias) @ Wcc, reduced over 128 cols
  float p0[8][4], p1[8][4];
#pragma unroll
  for (int mt = 0; mt < 8; ++mt)
#pragma unroll
    for (int r = 0; r < 4; ++r) { p0[mt][r] = 0.f; p1[mt][r] = 0.f; }
#pragma unroll
  for (int ntl = 0; ntl < 2; ++ntl) {
    const int colg = (wave * 2 + ntl) * 16 + m_l;
    const float bv = bias[colg];
    const float w0 = Wcc[colg * 2 + 0];
    const float w1 = Wcc[colg * 2 + 1];
#pragma unroll
    for (int mt = 0; mt < 8; ++mt)
#pragma unroll
      for (int r = 0; r < 4; ++r) {
        float hv = fmaxf(acc[ntl][mt][r] + bv, 0.f);   // relu(h1)
        p0[mt][r] += hv * w0;
        p1[mt][r] += hv * w1;
      }
  }
  // reduce across the 16 m_l lanes (columns); stays within the quad group
#pragma unroll
  for (int o = 1; o < 16; o <<= 1) {
#pragma unroll
    for (int mt = 0; mt < 8; ++mt)
#pragma unroll
      for (int r = 0; r < 4; ++r) {
        p0[mt][r] += __shfl_xor(p0[mt][r], o);
        p1[mt][r] += __shfl_xor(p1[mt][r], o);
      }
  }
  // cross-wave reduction via LDS (reuse staging buffer; dead after last barrier)
  float* zred = (float*)AhiS;   // [j][wave][quad][mt][r] = [2][4][4][8][4]
  if (m_l == 0) {
#pragma unroll
    for (int mt = 0; mt < 8; ++mt)
#pragma unroll
      for (int r = 0; r < 4; ++r) {
        zred[(((0 * 4 + wave) * 4 + quad) * 8 + mt) * 4 + r] = p0[mt][r];
        zred[(((1 * 4 + wave) * 4 + quad) * 8 + mt) * 4 + r] = p1[mt][r];
      }
  }
  __syncthreads();
  if (tid < 128) {
    // row-in-block = mt*16 + quad*4 + r == tid
    const int mt = tid >> 4, qd = (tid >> 2) & 3, r = tid & 3;
    const int rowg = m0 + tid;
    if (rowg < N_NODES) {
      float s0 = 0.f, s1 = 0.f;
#pragma unroll
      for (int w = 0; w < 4; ++w) {
        s0 += zred[(((0 * 4 + w) * 4 + qd) * 8 + mt) * 4 + r];
        s1 += zred[(((1 * 4 + w) * 4 + qd) * 8 + mt) * 4 + r];
      }
      float dn = dinv[rowg];
      tbl[rowg] = make_float4(dn * s0, dn * s1, dn, 0.f);
    }
  }
}

// ---------------- pass 1: yt[d] = dinv²·(zs[d] + Σ zs[s]),  g[d] = dinv·(Σ dinv + dinv)
// tbl[s] = (zs0, zs1, dinv[s], 0), 16 B/edge gather on a 1.6 MB (L2-resident) table.
__global__ __launch_bounds__(256)
void k_aggr1(const int* __restrict__ off, const int* __restrict__ csr,
             const float4* __restrict__ tbl, float2* __restrict__ tb2,
             float* __restrict__ g) {
  int node = blockIdx.x * 256 + threadIdx.x;
  if (node >= N_NODES) return;
  int start = (node == 0) ? 0 : off[node - 1];
  int end = off[node];
  float4 self = tbl[node];
  float s0 = self.x, s1 = self.y, sd = self.z;
  int e = start;
  for (; e + 3 < end; e += 4) {
    int i0 = csr[e], i1 = csr[e + 1], i2 = csr[e + 2], i3 = csr[e + 3];
    float4 v0 = tbl[i0];
    float4 v1 = tbl[i1];
    float4 v2 = tbl[i2];
    float4 v3 = tbl[i3];
    s0 += (v0.x + v1.x) + (v2.x + v3.x);
    s1 += (v0.y + v1.y) + (v2.y + v3.y);
    sd += (v0.z + v1.z) + (v2.z + v3.z);
  }
  for (; e < end; ++e) {
    float4 v = tbl[csr[e]];
    s0 += v.x; s1 += v.y; sd += v.z;
  }
  float dn = self.z;
  tb2[node] = make_float2(dn * dn * s0, dn * dn * s1);
  g[node] = dn * sd;
}

// ---------------- pass 2: out[d] = dinv·(yt[d] + Σ yt[s]) + g[d]·c1 + bc
// 8 B/edge gather on an 800 KB table. tail = {c1[0],c1[1],bc[0],bc[1]}.
__global__ __launch_bounds__(256)
void k_aggr2(const int* __restrict__ off, const int* __restrict__ csr,
             const float2* __restrict__ tb2, const float* __restrict__ dinv,
             const float* __restrict__ g, const float* __restrict__ tail,
             float* __restrict__ out) {
  int node = blockIdx.x * 256 + threadIdx.x;
  if (node >= N_NODES) return;
  int start = (node == 0) ? 0 : off[node - 1];
  int end = off[node];
  float2 self = tb2[node];
  float s0 = self.x, s1 = self.y;
  int e = start;
  for (; e + 3 < end; e += 4) {
    int i0 = csr[e], i1 = csr[e + 1], i2 = csr[e + 2], i3 = csr[e + 3];
    float2 v0 = tb2[i0];
    float2 v1 = tb2[i1];
    float2 v2 = tb2[i2];
    float2 v3 = tb2[i3];
    s0 += (v0.x + v1.x) + (v2.x + v3.x);
    s1 += (v0.y + v1.y) + (v2.y + v3.y);
  }
  for (; e < end; ++e) {
    float2 v = tb2[csr[e]];
    s0 += v.x; s1 += v.y;
  }
  float dn = dinv[node], gv = g[node];
  float o0 = dn * s0 + gv * tail[0] + tail[2];
  float o1 = dn * s1 + gv * tail[1] + tail[3];
  reinterpret_cast<float2*>(out)[node] = make_float2(o0, o1);
}

// --------------------------------------------- fp32 fallback (small ws) ----
__global__ __launch_bounds__(256) void k_count(const int* __restrict__ eidx,
                                               const int* __restrict__ flag,
                                               int* __restrict__ off) {
  int e = blockIdx.x * 256 + threadIdx.x;
  int is64 = *flag;
  if (e < N_EDGES) {
    unsigned d = (unsigned)get_dst(eidx, is64, e);
    if (d < N_NODES) atomicAdd(&off[d], 1);
  }
}

__global__ __launch_bounds__(256) void k_dinv_old(const int* __restrict__ off,
                                                  float* __restrict__ dinv) {
  int i = blockIdx.x * 256 + threadIdx.x;
  if (i < N_NODES) dinv[i] = rsqrtf(1.0f + (float)off[i]);
}

template <int K>
__global__ __launch_bounds__(256)
void k_gemm(const float* __restrict__ A, const float* __restrict__ B,
            const float* __restrict__ bias, const float* __restrict__ scale,
            float* __restrict__ C, const int do_relu) {
  __shared__ float As[64][33];
  const int tid = threadIdx.x;
  const int tx = tid & 15;
  const int ty = tid >> 4;
  const int m0 = blockIdx.x * 64;

  float acc[4][8];
#pragma unroll
  for (int i = 0; i < 4; ++i)
#pragma unroll
    for (int j = 0; j < 8; ++j) acc[i][j] = 0.f;

  const int rs = tid >> 2;
  const int ks = (tid & 3) * 8;

  for (int k0 = 0; k0 < K; k0 += 32) {
    float av8[8];
    const int gm = m0 + rs;
    if (gm < N_NODES) {
      load8(&A[(size_t)gm * K + k0 + ks], av8);
    } else {
#pragma unroll
      for (int j = 0; j < 8; ++j) av8[j] = 0.f;
    }
    __syncthreads();
#pragma unroll
    for (int j = 0; j < 8; ++j) As[rs][ks + j] = av8[j];
    __syncthreads();

    const float* Bp = B + (size_t)k0 * DIM_H + tx * 8;
#pragma unroll 4
    for (int k = 0; k < 32; ++k) {
      float bv[8];
      load8(Bp + (size_t)k * DIM_H, bv);
      float av[4];
#pragma unroll
      for (int rr = 0; rr < 4; ++rr) av[rr] = As[ty * 4 + rr][k];
#pragma unroll
      for (int rr = 0; rr < 4; ++rr)
#pragma unroll
        for (int cc = 0; cc < 8; ++cc)
          acc[rr][cc] = fmaf(av[rr], bv[cc], acc[rr][cc]);
    }
  }

  float bs[8];
  if (bias) {
    load8(bias + tx * 8, bs);
  } else {
#pragma unroll
    for (int j = 0; j < 8; ++j) bs[j] = 0.f;
  }
#pragma unroll
  for (int rr = 0; rr < 4; ++rr) {
    const int gm = m0 + ty * 4 + rr;
    if (gm < N_NODES) {
      float sc = scale ? scale[gm] : 1.0f;
      float v[8];
#pragma unroll
      for (int cc = 0; cc < 8; ++cc) {
        float t = acc[rr][cc] + bs[cc];
        if (do_relu) t = fmaxf(t, 0.f);
        v[cc] = t * sc;
      }
      float* Cp = &C[(size_t)gm * DIM_H + tx * 8];
      reinterpret_cast<float4*>(Cp)[0] = make_float4(v[0], v[1], v[2], v[3]);
      reinterpret_cast<float4*>(Cp)[1] = make_float4(v[4], v[5], v[6], v[7]);
    }
  }
}

__global__ __launch_bounds__(256)
void k_aggr_init(const float* __restrict__ t, const float* __restrict__ dinv,
                 const float* __restrict__ bias, float* __restrict__ h) {
  int idx = blockIdx.x * 256 + threadIdx.x;
  if (idx < N_NODES * DIM_H) {
    int i = idx >> 7;
    int c = idx & 127;
    float d = dinv[i];
    h[idx] = bias[c] + t[idx] * d * d;
  }
}

__global__ __launch_bounds__(256)
void k_aggr_edges(const int* __restrict__ eidx, const int* __restrict__ flag,
                  const float* __restrict__ t, const float* __restrict__ dinv,
                  float* __restrict__ h) {
  int e = blockIdx.x * 2 + (threadIdx.x >> 7);
  int c = threadIdx.x & 127;
  int is64 = *flag;
  if (e < N_EDGES) {
    unsigned s = (unsigned)get_src(eidx, is64, e);
    unsigned d = (unsigned)get_dst(eidx, is64, e);
    if (s < N_NODES && d < N_NODES) {
      float nrm = dinv[s] * dinv[d];
      unsafeAtomicAdd(&h[(size_t)d * DIM_H + c], t[(size_t)s * DIM_H + c] * nrm);
    }
  }
}

__global__ __launch_bounds__(256)
void k_head_f32(const float* __restrict__ h, const float* __restrict__ Wh,
                const float* __restrict__ bh, float* __restrict__ out) {
  int node = blockIdx.x * 4 + (threadIdx.x >> 6);
  int lane = threadIdx.x & 63;
  if (node >= N_NODES) return;
  float h0 = h[(size_t)node * DIM_H + lane];
  float h1 = h[(size_t)node * DIM_H + 64 + lane];
  float s0 = h0 * Wh[lane * 2 + 0] + h1 * Wh[(lane + 64) * 2 + 0];
  float s1 = h0 * Wh[lane * 2 + 1] + h1 * Wh[(lane + 64) * 2 + 1];
#pragma unroll
  for (int off = 32; off > 0; off >>= 1) {
    s0 += __shfl_down(s0, off);
    s1 += __shfl_down(s1, off);
  }
  if (lane == 0) {
    reinterpret_cast<float2*>(out)[node] = make_float2(s0 + bh[0], s1 + bh[1]);
  }
}

// ---------------------------------------------------------------- launch
extern "C" void kernel_launch(void* const* d_in, const int* in_sizes, int n_in,
                              void* d_out, int out_size, void* d_ws, size_t ws_size,
                              hipStream_t stream) {
  (void)in_sizes; (void)n_in; (void)out_size;
  const int* eidx = (const int*)d_in[0];
  const float* x  = (const float*)d_in[1];
  const float* Wi = (const float*)d_in[2];
  const float* bi = (const float*)d_in[3];
  const float* W1 = (const float*)d_in[4];
  const float* b1 = (const float*)d_in[5];
  const float* W2 = (const float*)d_in[6];
  const float* b2 = (const float*)d_in[7];
  const float* Wh = (const float*)d_in[8];
  const float* bh = (const float*)d_in[9];
  float* out = (float*)d_out;

  const int gE  = (N_EDGES + 255) / 256;
  const int gM  = (N_NODES + 63) / 64;
  const int gM2 = (N_NODES + 127) / 128;     // 782
  const int gW  = (N_NODES + 3) / 4;
  const int gN256 = (N_NODES + 255) / 256;

  char* ws = (char*)d_ws;
  int* flag = (int*)ws;

  const size_t need1 = 17410048;

  if (ws_size >= need1) {
    int*      bcnt  = (int*)(ws + 4096);
    int*      bbase = (int*)(ws + 57344);
    float*    Wcc   = (float*)(ws + 61440);     // 128x2 + c1[2] + bc[2]
    ushort*   bfWi  = (ushort*)(ws + 65536);    // 131072 B
    int*      off   = (int*)(ws + 262144);      // 400000 B
    float*    dinv  = (float*)(ws + 720896);    // 400000 B
    float*    g     = (float*)(ws + 1179648);   // 400000 B
    float4*   tbl   = (float4*)(ws + 1638400);  // 1600000 B
    float2*   tb2   = (float2*)(ws + 3407872);  // 800000 B
    int*      csr   = (int*)(ws + 4456448);     // 6400000 B
    unsigned* ebuf  = (unsigned*)(ws + 11010048); // 6400000 B

    // detect + bcnt zero (merged); bucketed CSR build
    k_init<<<1 + (NBKT * CPAD + 1023) / 1024, 1024, 0, stream>>>(eidx, flag, bcnt);
    k_binc<<<NBLK, 1024, 0, stream>>>(eidx, flag, bcnt);
    k_bscan<<<1, 1024, 0, stream>>>(bcnt, bbase);
    k_bin<<<NBLK, 1024, 0, stream>>>(eidx, flag, bcnt, ebuf);
    k_csr<<<NBKT, 256, 0, stream>>>(bbase, ebuf, off, dinv, csr);

    // weight prep: Wi fragments + collapsed tail Wcc = W1@W2@Wh (merged)
    k_prep<<<17, 256, 0, stream>>>(Wi, W1, W2, Wh, b1, b2, bh, bfWi, Wcc);

    // z = relu(x@Wi+bi) @ Wcc fused into GEMM epilogue -> tbl (N x float4)
    k_gemm_xz<DIM_IN><<<gM2, 256, 0, stream>>>(x, bfWi, bi, Wcc, dinv, tbl);
    // two cheap 8-16 B/edge aggregation passes (L2-resident tables)
    k_aggr1<<<gN256, 256, 0, stream>>>(off, csr, tbl, tb2, g);
    k_aggr2<<<gN256, 256, 0, stream>>>(off, csr, tb2, dinv, g, Wcc + 256, out);
  } else {
    // fallback: fp32 atomic-scatter path (~103 MB)
    const int gN  = (N_NODES + 255) / 256;
    int*   off  = (int*)(ws + 4096);
    float* dinv = (float*)(ws + 404480);
    float* fbA  = (float*)(ws + 804864);
    float* fbB  = (float*)(ws + 804864 + (size_t)N_NODES * DIM_H * 4);
    const int gNH = (N_NODES * DIM_H + 255) / 256;
    const int gE2 = (N_EDGES + 1) / 2;
    k_init<<<1, 1024, 0, stream>>>(eidx, flag, (int*)(ws + 4096));
    k_zero<<<gN, 256, 0, stream>>>(off, N_NODES);
    k_count<<<gE, 256, 0, stream>>>(eidx, flag, off);
    k_dinv_old<<<gN, 256, 0, stream>>>(off, dinv);

    k_gemm<DIM_IN><<<gM, 256, 0, stream>>>(x, Wi, bi, nullptr, fbA, 1);
    k_gemm<DIM_H><<<gM, 256, 0, stream>>>(fbA, W1, nullptr, nullptr, fbB, 0);
    k_aggr_init<<<gNH, 256, 0, stream>>>(fbB, dinv, b1, fbA);
    k_aggr_edges<<<gE2, 256, 0, stream>>>(eidx, flag, fbB, dinv, fbA);
    k_gemm<DIM_H><<<gM, 256, 0, stream>>>(fbA, W2, nullptr, nullptr, fbB, 0);
    k_aggr_init<<<gNH, 256, 0, stream>>>(fbB, dinv, b2, fbA);
    k_aggr_edges<<<gE2, 256, 0, stream>>>(eidx, flag, fbB, dinv, fbA);
    k_head_f32<<<gW, 256, 0, stream>>>(fbA, Wh, bh, out);
  }
}

// Round 6
// 285.320 us; speedup vs baseline: 1.0597x; 1.0323x over previous
//
#include <hip/hip_runtime.h>
#include <hip/hip_bf16.h>

#define N_NODES 100000
#define N_EDGES 1600000
#define DIM_IN  256
#define DIM_H   128

#define NBKT 782          // ceil(N_NODES / 128) buckets of 128 nodes
#define CPAD 16           // ints per padded counter (one cacheline)
#define EPB  8192         // edges per build block
#define NBLK ((N_EDGES + EPB - 1) / EPB)   // 196

typedef __attribute__((ext_vector_type(8))) short short8;
typedef __attribute__((ext_vector_type(4))) float f32x4;

__device__ __forceinline__ int get_src(const int* e, int is64, int i) {
  return is64 ? e[2 * i] : e[i];
}
__device__ __forceinline__ int get_dst(const int* e, int is64, int i) {
  return is64 ? e[2 * (N_EDGES + i)] : e[N_EDGES + i];
}

// ------------------------------------ width detect + bcnt zero (merged)
__global__ __launch_bounds__(1024)
void k_init(const int* __restrict__ e, int* __restrict__ flag,
            int* __restrict__ bcnt) {
  if (blockIdx.x == 0) {
    __shared__ int s;
    if (threadIdx.x == 0) s = 0;
    __syncthreads();
    atomicOr(&s, e[2 * threadIdx.x + 1]);
    __syncthreads();
    if (threadIdx.x == 0) *flag = (s == 0) ? 1 : 0;
  } else {
    int i = (blockIdx.x - 1) * 1024 + threadIdx.x;
    if (i < NBKT * CPAD) bcnt[i] = 0;
  }
}

__global__ __launch_bounds__(256) void k_zero(int* __restrict__ p, int n) {
  int i = blockIdx.x * 256 + threadIdx.x;
  if (i < n) p[i] = 0;
}

// ---------------------------------------------------- bucketed CSR build
__global__ __launch_bounds__(1024)
void k_binc(const int* __restrict__ eidx, const int* __restrict__ flag,
            int* __restrict__ bcnt) {
  __shared__ int hist[NBKT];
  const int t = threadIdx.x;
  const int is64 = *flag;
  for (int i = t; i < NBKT; i += 1024) hist[i] = 0;
  __syncthreads();
#pragma unroll
  for (int j = 0; j < EPB / 1024; ++j) {
    int e = blockIdx.x * EPB + j * 1024 + t;
    if (e < N_EDGES) {
      unsigned s = (unsigned)get_src(eidx, is64, e);
      unsigned d = (unsigned)get_dst(eidx, is64, e);
      if (s < N_NODES && d < N_NODES) atomicAdd(&hist[d >> 7], 1);
    }
  }
  __syncthreads();
  for (int i = t; i < NBKT; i += 1024) {
    int h = hist[i];
    if (h) atomicAdd(&bcnt[i * CPAD], h);
  }
}

__global__ __launch_bounds__(1024)
void k_bscan(int* __restrict__ bcnt, int* __restrict__ bbase) {
  __shared__ int sm[1024];
  int t = threadIdx.x;
  int v = (t < NBKT) ? bcnt[t * CPAD] : 0;
  sm[t] = v;
  __syncthreads();
  for (int d = 1; d < 1024; d <<= 1) {
    int u = (t >= d) ? sm[t - d] : 0;
    __syncthreads();
    sm[t] += u;
    __syncthreads();
  }
  if (t < NBKT) {
    int excl = sm[t] - v;
    bbase[t] = excl;
    bcnt[t * CPAD] = excl;
    if (t == NBKT - 1) bbase[NBKT] = sm[t];
  }
}

// record = src | (d&127)<<17   (src < 2^17)
__global__ __launch_bounds__(1024)
void k_bin(const int* __restrict__ eidx, const int* __restrict__ flag,
           int* __restrict__ bcnt, unsigned* __restrict__ ebuf) {
  __shared__ int hist[NBKT];
  __shared__ int cur[NBKT];
  const int t = threadIdx.x;
  const int is64 = *flag;
  for (int i = t; i < NBKT; i += 1024) hist[i] = 0;
  unsigned rec[EPB / 1024];
  int bkt[EPB / 1024];
  __syncthreads();
#pragma unroll
  for (int j = 0; j < EPB / 1024; ++j) {
    int e = blockIdx.x * EPB + j * 1024 + t;
    bkt[j] = -1;
    rec[j] = 0;
    if (e < N_EDGES) {
      unsigned s = (unsigned)get_src(eidx, is64, e);
      unsigned d = (unsigned)get_dst(eidx, is64, e);
      if (s < N_NODES && d < N_NODES) {
        bkt[j] = (int)(d >> 7);
        rec[j] = s | ((d & 127u) << 17);
        atomicAdd(&hist[bkt[j]], 1);
      }
    }
  }
  __syncthreads();
  for (int i = t; i < NBKT; i += 1024) {
    int h = hist[i];
    cur[i] = h ? atomicAdd(&bcnt[i * CPAD], h) : 0;
  }
  __syncthreads();
#pragma unroll
  for (int j = 0; j < EPB / 1024; ++j) {
    if (bkt[j] >= 0) {
      int pos = atomicAdd(&cur[bkt[j]], 1);
      ebuf[pos] = rec[j];
    }
  }
}

__global__ __launch_bounds__(256)
void k_csr(const int* __restrict__ bbase, const unsigned* __restrict__ ebuf,
           int* __restrict__ off, float* __restrict__ dinv,
           int* __restrict__ csr) {
  __shared__ int hist[128];
  __shared__ int scn[128];
  __shared__ int cur[128];
  const int b = blockIdx.x, t = threadIdx.x;
  const int n0 = b << 7;
  const int start = bbase[b], end = bbase[b + 1];
  if (t < 128) hist[t] = 0;
  __syncthreads();
  for (int i = start + t; i < end; i += 256) {
    atomicAdd(&hist[ebuf[i] >> 17], 1);
  }
  __syncthreads();
  if (t < 128) scn[t] = hist[t];
  __syncthreads();
  for (int d = 1; d < 128; d <<= 1) {
    int u = (t < 128 && t >= d) ? scn[t - d] : 0;
    __syncthreads();
    if (t < 128) scn[t] += u;
    __syncthreads();
  }
  if (t < 128) {
    int node = n0 + t;
    if (node < N_NODES) {
      off[node] = start + scn[t];                    // ends
      dinv[node] = rsqrtf(1.0f + (float)hist[t]);
      cur[t] = start + scn[t] - hist[t];             // starts
    }
  }
  __syncthreads();
  for (int i = start + t; i < end; i += 256) {
    unsigned r = ebuf[i];
    int pos = atomicAdd(&cur[r >> 17], 1);
    csr[pos] = (int)(r & 0x1FFFFu);
  }
}

// ---------------------------------------------------------------- bf16 utils
__device__ __forceinline__ ushort f2bf(float f) {
  unsigned u = __float_as_uint(f);
  unsigned r = (u + 0x7fffu + ((u >> 16) & 1u)) >> 16;
  return (ushort)r;
}
__device__ __forceinline__ float bf2f(ushort h) {
  return __uint_as_float(((unsigned)h) << 16);
}

__device__ __forceinline__ void load8(const float* p, float* o) {
  float4 a = reinterpret_cast<const float4*>(p)[0];
  float4 b = reinterpret_cast<const float4*>(p)[1];
  o[0] = a.x; o[1] = a.y; o[2] = a.z; o[3] = a.w;
  o[4] = b.x; o[5] = b.y; o[6] = b.z; o[7] = b.w;
}

__device__ __forceinline__ void cvt_split(const float* v, short8& h, short8& l) {
#pragma unroll
  for (int j = 0; j < 8; ++j) {
    ushort hb = f2bf(v[j]);
    ushort lb = f2bf(v[j] - bf2f(hb));
    h[j] = (short)hb;
    l[j] = (short)lb;
  }
}

// Blocks 0..15: split Wi[256x128] into MFMA B-fragment planes (hi, lo).
// Block 16: fully collapsed tail weights
//   Wcc = W1 @ (W2 @ Wh)  [128 x 2]   (everything after h1 is linear)
//   c1  = b1 @ (W2 @ Wh)  [2]         stored at Wcc[256..257]
//   bc  = b2 @ Wh + bh    [2]         stored at Wcc[258..259]
__global__ __launch_bounds__(256)
void k_prep(const float* __restrict__ Wi, const float* __restrict__ W1,
            const float* __restrict__ W2, const float* __restrict__ Wh,
            const float* __restrict__ b1, const float* __restrict__ b2,
            const float* __restrict__ bh, ushort* __restrict__ outHi,
            float* __restrict__ Wcc) {
  __shared__ float Wc2s[DIM_H][2];
  constexpr int CH = DIM_IN / 32;   // 8
  if (blockIdx.x == 16) {
    const int t = threadIdx.x;
    const int i = t >> 1, j = t & 1;
    float s = 0.f;
#pragma unroll 4
    for (int m = 0; m < DIM_H; ++m) s += W2[(size_t)i * DIM_H + m] * Wh[m * 2 + j];
    Wc2s[i][j] = s;
    __syncthreads();
    float c = 0.f;
#pragma unroll 4
    for (int k = 0; k < DIM_H; ++k) c += W1[(size_t)i * DIM_H + k] * Wc2s[k][j];
    Wcc[i * 2 + j] = c;
    if (t < 2) {
      float a = 0.f, b = 0.f;
      for (int k = 0; k < DIM_H; ++k) {
        a += b1[k] * Wc2s[k][t];
        b += b2[k] * Wh[k * 2 + t];
      }
      Wcc[256 + t] = a;           // c1
      Wcc[258 + t] = b + bh[t];   // bc
    }
    return;
  }
  int idx = blockIdx.x * 256 + threadIdx.x;   // < CH*512 = 4096
  int n  = idx & 15;
  int qq = (idx >> 4) & 3;
  int nt = (idx >> 6) & 7;
  int c  = idx >> 9;
  int col = nt * 16 + n;
  short8 h8, l8;
#pragma unroll
  for (int j = 0; j < 8; ++j) {
    float v = Wi[(size_t)(c * 32 + qq * 8 + j) * DIM_H + col];
    ushort hb = f2bf(v);
    ushort lb = f2bf(v - bf2f(hb));
    h8[j] = (short)hb;
    l8[j] = (short)lb;
  }
  ((short8*)outHi)[idx] = h8;
  ((short8*)outHi)[CH * 512 + idx] = l8;
}

// ------------- Cooperative MFMA GEMM, 64-row tile, double-buffered LDS with
// XOR-swizzled staging (bank-conflict-free writes AND reads), one barrier per
// K-step, A+B prefetch into registers; fused z = relu(.)@Wcc epilogue.
// 4 waves: each wave = 4 m-tiles x 2 col-tiles (24 MFMA / K-step).
// Swizzle: granule(row,q) = (row>>4)*64 + q*16 + ((row&15) ^ (q<<2)).
// Emits tbl[row] = (dinv*z0, dinv*z1, dinv, 0); h1 never materialized.
template <int K>
__global__ __launch_bounds__(256, 4)
void k_gemm_xz(const float* __restrict__ A, const ushort* __restrict__ Bfrag,
               const float* __restrict__ bias, const float* __restrict__ Wcc,
               const float* __restrict__ dinv, float4* __restrict__ tbl) {
  constexpr int CH = K / 32;   // 8
  __shared__ __align__(16) ushort AhiS[2][256 * 8];   // 8 KB (64 rows x 32 bf16 x 2 buf)
  __shared__ __align__(16) ushort AloS[2][256 * 8];   // 8 KB
  const int tid = threadIdx.x;
  const int m0 = blockIdx.x * 64;
  const int wave = tid >> 6, lane = tid & 63;
  const int m_l = lane & 15, quad = lane >> 4;
  const int rs = tid >> 2, q = tid & 3;

  f32x4 acc[2][4];
#pragma unroll
  for (int i = 0; i < 2; ++i)
#pragma unroll
    for (int j = 0; j < 4; ++j) acc[i][j] = (f32x4){0.f, 0.f, 0.f, 0.f};

  const short8* Bhi8 = (const short8*)Bfrag;
  const short8* Blo8 = Bhi8 + CH * 512;
  short8* Ah = (short8*)AhiS;
  short8* Al = (short8*)AloS;

  // each thread stages one (row, k-granule): row = rs (0..63), q = granule
  const int gr = m0 + rs;
  const float* Ap = &A[(size_t)((gr < N_NODES) ? gr : (N_NODES - 1)) * K + q * 8];
  const int went = (rs >> 4) * 64 + q * 16 + ((rs & 15) ^ (q << 2));   // swizzled write
  const int rent = quad * 16 + (m_l ^ (quad << 2));                     // + mt*64 on read

  // prologue: stage c=0 into buf 0; preload B for c=0
  {
    float v[8];
    load8(Ap, v);
    short8 h, l;
    cvt_split(v, h, l);
    Ah[went] = h;
    Al[went] = l;
  }
  const int bq = quad * 16 + m_l;
  short8 bh0 = Bhi8[(wave * 2 + 0) * 64 + bq];
  short8 bl0 = Blo8[(wave * 2 + 0) * 64 + bq];
  short8 bh1 = Bhi8[(wave * 2 + 1) * 64 + bq];
  short8 bl1 = Blo8[(wave * 2 + 1) * 64 + bq];
  __syncthreads();

#pragma unroll
  for (int c = 0; c < CH; ++c) {
    const int cur = c & 1, nxt = cur ^ 1;
    // prefetch next K-chunk (A) and next B fragments into registers
    float vn[8];
    short8 nbh0, nbl0, nbh1, nbl1;
    if (c + 1 < CH) {
      load8(Ap + (c + 1) * 32, vn);
      const int b0 = ((c + 1) * 8 + wave * 2 + 0) * 64 + bq;
      const int b1 = ((c + 1) * 8 + wave * 2 + 1) * 64 + bq;
      nbh0 = Bhi8[b0]; nbl0 = Blo8[b0];
      nbh1 = Bhi8[b1]; nbl1 = Blo8[b1];
    }
    const short8* AhC = Ah + cur * 256;
    const short8* AlC = Al + cur * 256;
#pragma unroll
    for (int mt = 0; mt < 4; ++mt) {
      short8 ahi = AhC[mt * 64 + rent];
      short8 alo = AlC[mt * 64 + rent];
      acc[0][mt] = __builtin_amdgcn_mfma_f32_16x16x32_bf16(ahi, bh0, acc[0][mt], 0, 0, 0);
      acc[0][mt] = __builtin_amdgcn_mfma_f32_16x16x32_bf16(ahi, bl0, acc[0][mt], 0, 0, 0);
      acc[0][mt] = __builtin_amdgcn_mfma_f32_16x16x32_bf16(alo, bh0, acc[0][mt], 0, 0, 0);
      acc[1][mt] = __builtin_amdgcn_mfma_f32_16x16x32_bf16(ahi, bh1, acc[1][mt], 0, 0, 0);
      acc[1][mt] = __builtin_amdgcn_mfma_f32_16x16x32_bf16(ahi, bl1, acc[1][mt], 0, 0, 0);
      acc[1][mt] = __builtin_amdgcn_mfma_f32_16x16x32_bf16(alo, bh1, acc[1][mt], 0, 0, 0);
    }
    // convert + store next chunk into the other buffer; rotate B regs
    if (c + 1 < CH) {
      short8 h, l;
      cvt_split(vn, h, l);
      Ah[nxt * 256 + went] = h;
      Al[nxt * 256 + went] = l;
      bh0 = nbh0; bl0 = nbl0; bh1 = nbh1; bl1 = nbl1;
    }
    __syncthreads();
  }

  // ---- fused epilogue: p = relu(acc + bias) @ Wcc, reduced over 128 cols
  float p0[4][4], p1[4][4];
#pragma unroll
  for (int mt = 0; mt < 4; ++mt)
#pragma unroll
    for (int r = 0; r < 4; ++r) { p0[mt][r] = 0.f; p1[mt][r] = 0.f; }
#pragma unroll
  for (int ntl = 0; ntl < 2; ++ntl) {
    const int colg = (wave * 2 + ntl) * 16 + m_l;
    const float bv = bias[colg];
    const float w0 = Wcc[colg * 2 + 0];
    const float w1 = Wcc[colg * 2 + 1];
#pragma unroll
    for (int mt = 0; mt < 4; ++mt)
#pragma unroll
      for (int r = 0; r < 4; ++r) {
        float hv = fmaxf(acc[ntl][mt][r] + bv, 0.f);   // relu(h1)
        p0[mt][r] += hv * w0;
        p1[mt][r] += hv * w1;
      }
  }
  // reduce across the 16 m_l lanes (columns); stays within the quad group
#pragma unroll
  for (int o = 1; o < 16; o <<= 1) {
#pragma unroll
    for (int mt = 0; mt < 4; ++mt)
#pragma unroll
      for (int r = 0; r < 4; ++r) {
        p0[mt][r] += __shfl_xor(p0[mt][r], o);
        p1[mt][r] += __shfl_xor(p1[mt][r], o);
      }
  }
  // cross-wave reduction via LDS (staging dead after final barrier above)
  float* zred = (float*)AhiS;   // [j][wave][quad][mt][r] = [2][4][4][4][4]
  if (m_l == 0) {
#pragma unroll
    for (int mt = 0; mt < 4; ++mt)
#pragma unroll
      for (int r = 0; r < 4; ++r) {
        zred[(((0 * 4 + wave) * 4 + quad) * 4 + mt) * 4 + r] = p0[mt][r];
        zred[(((1 * 4 + wave) * 4 + quad) * 4 + mt) * 4 + r] = p1[mt][r];
      }
  }
  __syncthreads();
  if (tid < 64) {
    // row-in-block = mt*16 + quad*4 + r == tid
    const int mt = tid >> 4, qd = (tid >> 2) & 3, r = tid & 3;
    const int rowg = m0 + tid;
    if (rowg < N_NODES) {
      float s0 = 0.f, s1 = 0.f;
#pragma unroll
      for (int w = 0; w < 4; ++w) {
        s0 += zred[(((0 * 4 + w) * 4 + qd) * 4 + mt) * 4 + r];
        s1 += zred[(((1 * 4 + w) * 4 + qd) * 4 + mt) * 4 + r];
      }
      float dn = dinv[rowg];
      tbl[rowg] = make_float4(dn * s0, dn * s1, dn, 0.f);
    }
  }
}

// ---------------- pass 1: yt[d] = dinv²·(zs[d] + Σ zs[s]),  g[d] = dinv·(Σ dinv + dinv)
// tbl[s] = (zs0, zs1, dinv[s], 0), 16 B/edge gather on a 1.6 MB (L2-resident) table.
__global__ __launch_bounds__(256)
void k_aggr1(const int* __restrict__ off, const int* __restrict__ csr,
             const float4* __restrict__ tbl, float2* __restrict__ tb2,
             float* __restrict__ g) {
  int node = blockIdx.x * 256 + threadIdx.x;
  if (node >= N_NODES) return;
  int start = (node == 0) ? 0 : off[node - 1];
  int end = off[node];
  float4 self = tbl[node];
  float s0 = self.x, s1 = self.y, sd = self.z;
  int e = start;
  for (; e + 3 < end; e += 4) {
    int i0 = csr[e], i1 = csr[e + 1], i2 = csr[e + 2], i3 = csr[e + 3];
    float4 v0 = tbl[i0];
    float4 v1 = tbl[i1];
    float4 v2 = tbl[i2];
    float4 v3 = tbl[i3];
    s0 += (v0.x + v1.x) + (v2.x + v3.x);
    s1 += (v0.y + v1.y) + (v2.y + v3.y);
    sd += (v0.z + v1.z) + (v2.z + v3.z);
  }
  for (; e < end; ++e) {
    float4 v = tbl[csr[e]];
    s0 += v.x; s1 += v.y; sd += v.z;
  }
  float dn = self.z;
  tb2[node] = make_float2(dn * dn * s0, dn * dn * s1);
  g[node] = dn * sd;
}

// ---------------- pass 2: out[d] = dinv·(yt[d] + Σ yt[s]) + g[d]·c1 + bc
// 8 B/edge gather on an 800 KB table. tail = {c1[0],c1[1],bc[0],bc[1]}.
__global__ __launch_bounds__(256)
void k_aggr2(const int* __restrict__ off, const int* __restrict__ csr,
             const float2* __restrict__ tb2, const float* __restrict__ dinv,
             const float* __restrict__ g, const float* __restrict__ tail,
             float* __restrict__ out) {
  int node = blockIdx.x * 256 + threadIdx.x;
  if (node >= N_NODES) return;
  int start = (node == 0) ? 0 : off[node - 1];
  int end = off[node];
  float2 self = tb2[node];
  float s0 = self.x, s1 = self.y;
  int e = start;
  for (; e + 3 < end; e += 4) {
    int i0 = csr[e], i1 = csr[e + 1], i2 = csr[e + 2], i3 = csr[e + 3];
    float2 v0 = tb2[i0];
    float2 v1 = tb2[i1];
    float2 v2 = tb2[i2];
    float2 v3 = tb2[i3];
    s0 += (v0.x + v1.x) + (v2.x + v3.x);
    s1 += (v0.y + v1.y) + (v2.y + v3.y);
  }
  for (; e < end; ++e) {
    float2 v = tb2[csr[e]];
    s0 += v.x; s1 += v.y;
  }
  float dn = dinv[node], gv = g[node];
  float o0 = dn * s0 + gv * tail[0] + tail[2];
  float o1 = dn * s1 + gv * tail[1] + tail[3];
  reinterpret_cast<float2*>(out)[node] = make_float2(o0, o1);
}

// --------------------------------------------- fp32 fallback (small ws) ----
__global__ __launch_bounds__(256) void k_count(const int* __restrict__ eidx,
                                               const int* __restrict__ flag,
                                               int* __restrict__ off) {
  int e = blockIdx.x * 256 + threadIdx.x;
  int is64 = *flag;
  if (e < N_EDGES) {
    unsigned d = (unsigned)get_dst(eidx, is64, e);
    if (d < N_NODES) atomicAdd(&off[d], 1);
  }
}

__global__ __launch_bounds__(256) void k_dinv_old(const int* __restrict__ off,
                                                  float* __restrict__ dinv) {
  int i = blockIdx.x * 256 + threadIdx.x;
  if (i < N_NODES) dinv[i] = rsqrtf(1.0f + (float)off[i]);
}

template <int K>
__global__ __launch_bounds__(256)
void k_gemm(const float* __restrict__ A, const float* __restrict__ B,
            const float* __restrict__ bias, const float* __restrict__ scale,
            float* __restrict__ C, const int do_relu) {
  __shared__ float As[64][33];
  const int tid = threadIdx.x;
  const int tx = tid & 15;
  const int ty = tid >> 4;
  const int m0 = blockIdx.x * 64;

  float acc[4][8];
#pragma unroll
  for (int i = 0; i < 4; ++i)
#pragma unroll
    for (int j = 0; j < 8; ++j) acc[i][j] = 0.f;

  const int rs = tid >> 2;
  const int ks = (tid & 3) * 8;

  for (int k0 = 0; k0 < K; k0 += 32) {
    float av8[8];
    const int gm = m0 + rs;
    if (gm < N_NODES) {
      load8(&A[(size_t)gm * K + k0 + ks], av8);
    } else {
#pragma unroll
      for (int j = 0; j < 8; ++j) av8[j] = 0.f;
    }
    __syncthreads();
#pragma unroll
    for (int j = 0; j < 8; ++j) As[rs][ks + j] = av8[j];
    __syncthreads();

    const float* Bp = B + (size_t)k0 * DIM_H + tx * 8;
#pragma unroll 4
    for (int k = 0; k < 32; ++k) {
      float bv[8];
      load8(Bp + (size_t)k * DIM_H, bv);
      float av[4];
#pragma unroll
      for (int rr = 0; rr < 4; ++rr) av[rr] = As[ty * 4 + rr][k];
#pragma unroll
      for (int rr = 0; rr < 4; ++rr)
#pragma unroll
        for (int cc = 0; cc < 8; ++cc)
          acc[rr][cc] = fmaf(av[rr], bv[cc], acc[rr][cc]);
    }
  }

  float bs[8];
  if (bias) {
    load8(bias + tx * 8, bs);
  } else {
#pragma unroll
    for (int j = 0; j < 8; ++j) bs[j] = 0.f;
  }
#pragma unroll
  for (int rr = 0; rr < 4; ++rr) {
    const int gm = m0 + ty * 4 + rr;
    if (gm < N_NODES) {
      float sc = scale ? scale[gm] : 1.0f;
      float v[8];
#pragma unroll
      for (int cc = 0; cc < 8; ++cc) {
        float t = acc[rr][cc] + bs[cc];
        if (do_relu) t = fmaxf(t, 0.f);
        v[cc] = t * sc;
      }
      float* Cp = &C[(size_t)gm * DIM_H + tx * 8];
      reinterpret_cast<float4*>(Cp)[0] = make_float4(v[0], v[1], v[2], v[3]);
      reinterpret_cast<float4*>(Cp)[1] = make_float4(v[4], v[5], v[6], v[7]);
    }
  }
}

__global__ __launch_bounds__(256)
void k_aggr_init(const float* __restrict__ t, const float* __restrict__ dinv,
                 const float* __restrict__ bias, float* __restrict__ h) {
  int idx = blockIdx.x * 256 + threadIdx.x;
  if (idx < N_NODES * DIM_H) {
    int i = idx >> 7;
    int c = idx & 127;
    float d = dinv[i];
    h[idx] = bias[c] + t[idx] * d * d;
  }
}

__global__ __launch_bounds__(256)
void k_aggr_edges(const int* __restrict__ eidx, const int* __restrict__ flag,
                  const float* __restrict__ t, const float* __restrict__ dinv,
                  float* __restrict__ h) {
  int e = blockIdx.x * 2 + (threadIdx.x >> 7);
  int c = threadIdx.x & 127;
  int is64 = *flag;
  if (e < N_EDGES) {
    unsigned s = (unsigned)get_src(eidx, is64, e);
    unsigned d = (unsigned)get_dst(eidx, is64, e);
    if (s < N_NODES && d < N_NODES) {
      float nrm = dinv[s] * dinv[d];
      unsafeAtomicAdd(&h[(size_t)d * DIM_H + c], t[(size_t)s * DIM_H + c] * nrm);
    }
  }
}

__global__ __launch_bounds__(256)
void k_head_f32(const float* __restrict__ h, const float* __restrict__ Wh,
                const float* __restrict__ bh, float* __restrict__ out) {
  int node = blockIdx.x * 4 + (threadIdx.x >> 6);
  int lane = threadIdx.x & 63;
  if (node >= N_NODES) return;
  float h0 = h[(size_t)node * DIM_H + lane];
  float h1 = h[(size_t)node * DIM_H + 64 + lane];
  float s0 = h0 * Wh[lane * 2 + 0] + h1 * Wh[(lane + 64) * 2 + 0];
  float s1 = h0 * Wh[lane * 2 + 1] + h1 * Wh[(lane + 64) * 2 + 1];
#pragma unroll
  for (int off = 32; off > 0; off >>= 1) {
    s0 += __shfl_down(s0, off);
    s1 += __shfl_down(s1, off);
  }
  if (lane == 0) {
    reinterpret_cast<float2*>(out)[node] = make_float2(s0 + bh[0], s1 + bh[1]);
  }
}

// ---------------------------------------------------------------- launch
extern "C" void kernel_launch(void* const* d_in, const int* in_sizes, int n_in,
                              void* d_out, int out_size, void* d_ws, size_t ws_size,
                              hipStream_t stream) {
  (void)in_sizes; (void)n_in; (void)out_size;
  const int* eidx = (const int*)d_in[0];
  const float* x  = (const float*)d_in[1];
  const float* Wi = (const float*)d_in[2];
  const float* bi = (const float*)d_in[3];
  const float* W1 = (const float*)d_in[4];
  const float* b1 = (const float*)d_in[5];
  const float* W2 = (const float*)d_in[6];
  const float* b2 = (const float*)d_in[7];
  const float* Wh = (const float*)d_in[8];
  const float* bh = (const float*)d_in[9];
  float* out = (float*)d_out;

  const int gE  = (N_EDGES + 255) / 256;
  const int gM  = (N_NODES + 63) / 64;       // 1563
  const int gW  = (N_NODES + 3) / 4;
  const int gN256 = (N_NODES + 255) / 256;

  char* ws = (char*)d_ws;
  int* flag = (int*)ws;

  const size_t need1 = 17410048;

  if (ws_size >= need1) {
    int*      bcnt  = (int*)(ws + 4096);
    int*      bbase = (int*)(ws + 57344);
    float*    Wcc   = (float*)(ws + 61440);     // 128x2 + c1[2] + bc[2]
    ushort*   bfWi  = (ushort*)(ws + 65536);    // 131072 B
    int*      off   = (int*)(ws + 262144);      // 400000 B
    float*    dinv  = (float*)(ws + 720896);    // 400000 B
    float*    g     = (float*)(ws + 1179648);   // 400000 B
    float4*   tbl   = (float4*)(ws + 1638400);  // 1600000 B
    float2*   tb2   = (float2*)(ws + 3407872);  // 800000 B
    int*      csr   = (int*)(ws + 4456448);     // 6400000 B
    unsigned* ebuf  = (unsigned*)(ws + 11010048); // 6400000 B

    // detect + bcnt zero (merged); bucketed CSR build
    k_init<<<1 + (NBKT * CPAD + 1023) / 1024, 1024, 0, stream>>>(eidx, flag, bcnt);
    k_binc<<<NBLK, 1024, 0, stream>>>(eidx, flag, bcnt);
    k_bscan<<<1, 1024, 0, stream>>>(bcnt, bbase);
    k_bin<<<NBLK, 1024, 0, stream>>>(eidx, flag, bcnt, ebuf);
    k_csr<<<NBKT, 256, 0, stream>>>(bbase, ebuf, off, dinv, csr);

    // weight prep: Wi fragments + collapsed tail Wcc = W1@W2@Wh (merged)
    k_prep<<<17, 256, 0, stream>>>(Wi, W1, W2, Wh, b1, b2, bh, bfWi, Wcc);

    // z = relu(x@Wi+bi) @ Wcc fused into GEMM epilogue -> tbl (N x float4)
    k_gemm_xz<DIM_IN><<<gM, 256, 0, stream>>>(x, bfWi, bi, Wcc, dinv, tbl);
    // two cheap 8-16 B/edge aggregation passes (L2-resident tables)
    k_aggr1<<<gN256, 256, 0, stream>>>(off, csr, tbl, tb2, g);
    k_aggr2<<<gN256, 256, 0, stream>>>(off, csr, tb2, dinv, g, Wcc + 256, out);
  } else {
    // fallback: fp32 atomic-scatter path (~103 MB)
    const int gN  = (N_NODES + 255) / 256;
    int*   off  = (int*)(ws + 4096);
    float* dinv = (float*)(ws + 404480);
    float* fbA  = (float*)(ws + 804864);
    float* fbB  = (float*)(ws + 804864 + (size_t)N_NODES * DIM_H * 4);
    const int gNH = (N_NODES * DIM_H + 255) / 256;
    const int gE2 = (N_EDGES + 1) / 2;
    k_init<<<1, 1024, 0, stream>>>(eidx, flag, (int*)(ws + 4096));
    k_zero<<<gN, 256, 0, stream>>>(off, N_NODES);
    k_count<<<gE, 256, 0, stream>>>(eidx, flag, off);
    k_dinv_old<<<gN, 256, 0, stream>>>(off, dinv);

    k_gemm<DIM_IN><<<gM, 256, 0, stream>>>(x, Wi, bi, nullptr, fbA, 1);
    k_gemm<DIM_H><<<gM, 256, 0, stream>>>(fbA, W1, nullptr, nullptr, fbB, 0);
    k_aggr_init<<<gNH, 256, 0, stream>>>(fbB, dinv, b1, fbA);
    k_aggr_edges<<<gE2, 256, 0, stream>>>(eidx, flag, fbB, dinv, fbA);
    k_gemm<DIM_H><<<gM, 256, 0, stream>>>(fbA, W2, nullptr, nullptr, fbB, 0);
    k_aggr_init<<<gNH, 256, 0, stream>>>(fbB, dinv, b2, fbA);
    k_aggr_edges<<<gE2, 256, 0, stream>>>(eidx, flag, fbB, dinv, fbA);
    k_head_f32<<<gW, 256, 0, stream>>>(fbA, Wh, bh, out);
  }
}